// Round 6
// baseline (193.249 us; speedup 1.0000x reference)
//
#include <hip/hip_runtime.h>
#include <stdint.h>

typedef unsigned long long u64;
typedef unsigned int u32;

#define BATCH 32
#define NCH 84
#define NA 8400
#define NCLS 80
#define TOPK 1000
#define MAXDET 300
#define CONF 0.25f
#define IOU_T 0.7f
#define MAX_WH 7680.0f
#define IMG_SZ 640.0f
#define NT 1024
#define KPT 9            // ceil(NA / NT)
#define NCOPY 8          // privatized histogram copies
#define HPAD 260         // 16B-aligned rows, bank-staggered copies

__device__ __constant__ float coco_map_f[NCLS] = {
    1,2,3,4,5,6,7,8,9,10,11,13,14,15,16,17,18,19,20,21,22,23,24,25,27,28,
    31,32,33,34,35,36,37,38,39,40,41,42,43,44,46,47,48,49,50,51,52,53,54,
    55,56,57,58,59,60,61,62,63,64,65,67,70,72,73,74,75,76,77,78,79,80,81,
    82,84,85,86,87,88,89,90};

__device__ inline u64 shflx64(u64 v, int m) {
    int lo = __shfl_xor((int)(u32)(v & 0xFFFFFFFFull), m, 64);
    int hi = __shfl_xor((int)(u32)(v >> 32), m, 64);
    return ((u64)(u32)hi << 32) | (u32)lo;
}

// ---------------- K1: decode 4 anchors/thread via float4 ---------------------
__global__ __launch_bounds__(256)
void decode_kernel(const float* __restrict__ preds,
                   u64* __restrict__ keys,
                   float4* __restrict__ boxes,
                   int* __restrict__ labels) {
    const int QPB = NA / 4;                       // 2100 quads per batch
    int gid = blockIdx.x * 256 + threadIdx.x;
    if (gid >= BATCH * QPB) return;
    int b = gid / QPB;
    int q = gid - b * QPB;
    int a0 = q * 4;
    const float* p = preds + (size_t)b * NCH * NA + a0;

    float4 x = *(const float4*)(p);
    float4 y = *(const float4*)(p + NA);
    float4 w = *(const float4*)(p + 2 * NA);
    float4 h = *(const float4*)(p + 3 * NA);

    float4 best = *(const float4*)(p + 4 * NA);
    int lx = 0, ly = 0, lz = 0, lw = 0;
#pragma unroll 16
    for (int c = 1; c < NCLS; ++c) {
        const float4 v = *(const float4*)(p + (size_t)(4 + c) * NA);
        lx = (v.x > best.x) ? c : lx;  best.x = fmaxf(v.x, best.x);
        ly = (v.y > best.y) ? c : ly;  best.y = fmaxf(v.y, best.y);
        lz = (v.z > best.z) ? c : lz;  best.z = fmaxf(v.z, best.z);
        lw = (v.w > best.w) ? c : lw;  best.w = fmaxf(v.w, best.w);
    }

    float bs[4] = {best.x, best.y, best.z, best.w};
    int   bl[4] = {lx, ly, lz, lw};
    float cx[4] = {x.x, x.y, x.z, x.w};
    float cy[4] = {y.x, y.y, y.z, y.w};
    float cw[4] = {w.x, w.y, w.z, w.w};
    float ch[4] = {h.x, h.y, h.z, h.w};

    u64* kp = keys + (size_t)b * NA + a0;
    float4* bp = boxes + (size_t)b * NA + a0;
    int* lp = labels + (size_t)b * NA + a0;

#pragma unroll
    for (int i = 0; i < 4; ++i) {
        float fx = cx[i] * IMG_SZ, fy = cy[i] * IMG_SZ;
        float fw = cw[i] * IMG_SZ, fh = ch[i] * IMG_SZ;
        float hw = fw * 0.5f, hh = fh * 0.5f;
        bp[i] = make_float4(fx - hw, fy - hh, fx + hw, fy + hh);
        float s = (bs[i] > CONF) ? bs[i] : -1.0f;
        u32 fb = __float_as_uint(s);
        u32 u = (fb & 0x80000000u) ? ~fb : (fb | 0x80000000u);
        // 46-bit key: sortable score bits << 14 | inverted anchor index
        kp[i] = ((u64)u << 14) | (u64)(16383 - (a0 + i));
    }
    *(int4*)lp = make_int4(bl[0], bl[1], bl[2], bl[3]);
}

// ---------------- K2: per-batch radix-select + sort + NMS + output ----------
__global__ __launch_bounds__(NT)
void select_nms_kernel(const u64* __restrict__ keys,
                       const float4* __restrict__ boxes,
                       const int* __restrict__ labels,
                       float* __restrict__ out) {
    const int b = blockIdx.x;
    const int t = threadIdx.x;
    const int lane = t & 63, wid = t >> 6;

    __shared__ u64 skey[NT];                        // 8 KB   (bitonic exchange)
    __shared__ float offb[TOPK][4];                 // 16 KB  (offset boxes)
    __shared__ float area_s[TOPK];                  // 4 KB
    __shared__ unsigned char lb8[TOPK];             // 1 KB
    __shared__ unsigned char keep[TOPK];            // 1 KB
    __shared__ u64 cmask2[NCLS][16];                // 10 KB  (class membership)
    __shared__ unsigned short rows[NCLS][64];       // 10 KB  (per-class rank lists)
    __shared__ int sh_hist[NCOPY * HPAD];           // 8.3 KB
    __shared__ int selB, selK, hselS, cnt, nselS, ktot_s;
    __shared__ int wsum[16], woff[16];

    // ---- load this batch's keys (<=9 per thread, stays in VGPRs) ----
    u64 kreg[KPT];
    const u64* kb = keys + (size_t)b * NA;
    int nk = 0;
    for (int i = t; i < NA; i += NT) kreg[nk++] = kb[i];

    // ---- MSB-first radix select with early exit (candidates <= 1024) ----
    u64 P = 0ull;
    int kk = TOPK;
    int nsel = 0;
    for (int d = 5; d >= 0; --d) {
        for (int i = t; i < NCOPY * HPAD; i += NT) sh_hist[i] = 0;
        __syncthreads();
        u64 hmask = (~0ull) << (8 * (d + 1));
        int* myh = sh_hist + (wid & (NCOPY - 1)) * HPAD;
        for (int i = 0; i < KPT; ++i) {
            if (i < nk) {
                u64 key = kreg[i];
                if (((key ^ P) & hmask) == 0ull)
                    atomicAdd(&myh[(int)((key >> (8 * d)) & 255)], 1);
            }
        }
        __syncthreads();
        if (t < 64) {
            int h0 = 0, h1 = 0, h2 = 0, h3 = 0;
            for (int c = 0; c < NCOPY; ++c) {
                const int* hp = sh_hist + c * HPAD + 4 * t;   // 16B-aligned
                h0 += hp[0]; h1 += hp[1]; h2 += hp[2]; h3 += hp[3];
            }
            int s = h0 + h1 + h2 + h3;
            int S = s;                       // wave suffix-scan, no barriers
            #pragma unroll
            for (int off = 1; off < 64; off <<= 1) {
                int o = __shfl_down(S, off, 64);
                if (t + off < 64) S += o;
            }
            int Snext = S - s;
            int c3 = Snext + h3, c2 = c3 + h2, c1 = c2 + h1, c0 = c1 + h0;
            int cand = -1, above = 0;
            if (c0 >= kk) {
                if      (c3 >= kk) { cand = 4 * t + 3; above = Snext; }
                else if (c2 >= kk) { cand = 4 * t + 2; above = c3; }
                else if (c1 >= kk) { cand = 4 * t + 1; above = c2; }
                else               { cand = 4 * t;     above = c1; }
            }
            int pc = (cand < 0) ? 0 : (((cand + 1) << 16) | (kk - above));
            #pragma unroll
            for (int off = 32; off; off >>= 1)
                pc = max(pc, __shfl_down(pc, off, 64));
            pc = __shfl(pc, 0, 64);          // broadcast winner to all lanes
            int B = (pc >> 16) - 1;
            if (t == (B >> 2)) {
                int m4 = B & 3;
                selB = B;
                selK = pc & 0xFFFF;
                hselS = (m4 == 0) ? h0 : (m4 == 1) ? h1 : (m4 == 2) ? h2 : h3;
            }
        }
        __syncthreads();
        P |= ((u64)selB) << (8 * d);
        kk = selK;
        nsel = TOPK - kk + hselS;            // candidates if we stop here
        if (nsel <= NT) break;               // typical: after ~3 passes
        __syncthreads();                     // protect selB/selK/hselS reuse
    }

    // ---- compact the nsel (1000..1024) keys >= P (wave-aggregated) ----
    if (t == 0) cnt = 0;
    __syncthreads();
    for (int i = 0; i < KPT; ++i) {
        bool p = (i < nk) && (kreg[i] >= P);
        u64 m = __ballot(p);
        int base = 0;
        if (lane == 0) base = atomicAdd(&cnt, (int)__popcll(m));
        base = __shfl(base, 0, 64);
        if (p) skey[base + (int)__popcll(m & ((1ull << lane) - 1ull))] = kreg[i];
    }
    if (t < NT - nsel) skey[nsel + t] = 0ull;
    __syncthreads();

    // ---- hybrid bitonic sort, descending: shfl_xor for stride<64 ----
    u64 myk = skey[t];
    for (int size = 2; size <= NT; size <<= 1) {
        bool up = ((t & size) == 0);
        for (int stride = size >> 1; stride; stride >>= 1) {
            u64 pk;
            if (stride >= 64) {
                __syncthreads(); skey[t] = myk; __syncthreads();
                pk = skey[t ^ stride];
            } else {
                pk = shflx64(myk, stride);
            }
            bool tlow = ((t & stride) == 0);
            u64 mn = (myk < pk) ? myk : pk;
            u64 mx = (myk < pk) ? pk : myk;
            myk = up ? (tlow ? mx : mn) : (tlow ? mn : mx);
        }
    }
    // myk == sorted key at rank t; ranks 0..999 are the exact top-1000.

    for (int i = t; i < NCLS * 16; i += NT) ((u64*)cmask2)[i] = 0ull;
    __syncthreads();

    // ---- gather payloads for sorted rank t ----
    int my_a = -1, my_L = 0;
    if (t < TOPK) {
        my_a = 16383 - (int)(myk & 16383ull);
        my_L = labels[(size_t)b * NA + my_a];
        lb8[t] = (unsigned char)my_L;
        float4 bx = boxes[(size_t)b * NA + my_a];
        float off = (float)my_L * MAX_WH;
        float ox0 = bx.x + off, oy0 = bx.y + off, ox1 = bx.z + off, oy1 = bx.w + off;
        offb[t][0] = ox0; offb[t][1] = oy0; offb[t][2] = ox1; offb[t][3] = oy1;
        area_s[t] = (ox1 - ox0) * (oy1 - oy0);   // ref: area on offset boxes
        keep[t] = 1;
        atomicOr(&cmask2[my_L][t >> 6], 1ull << (t & 63));
    }
    __syncthreads();

    // ---- NMS: one wave per class; membership from bitmask, boxes in regs ----
    for (int c = wid; c < NCLS; c += 16) {
        u64 w = (lane < 16) ? cmask2[c][lane] : 0ull;
        int cw = __popcll(w);
        int pre = cw;
        #pragma unroll
        for (int off = 1; off < 16; off <<= 1) {
            int o = __shfl_up(pre, off, 64);
            if (lane >= off) pre += o;
        }
        int n = __shfl(pre, 15, 64);
        pre -= cw;                           // exclusive prefix
        if (n == 0) continue;
        if (n <= 64) {
            if (lane < 16) {                 // emit rank list from mask bits
                u64 ww = w; int base = pre, boff = lane << 6;
                while (ww) {
                    int bit = __ffsll((long long)ww) - 1;
                    ww &= ww - 1;
                    rows[c][base++] = (unsigned short)(boff + bit);
                }
            }
            int j = (lane < n) ? (int)rows[c][lane] : (int)rows[c][0];
            float x0 = offb[j][0], y0 = offb[j][1];
            float x1 = offb[j][2], y1 = offb[j][3];
            float ar = area_s[j];
            // phase 1: colmask (no loop-carried dependence -> pipelined)
            u64 colm = 0ull;
            for (int i = 0; i < n; ++i) {
                float hx0 = __shfl(x0, i, 64);
                float hy0 = __shfl(y0, i, 64);
                float hx1 = __shfl(x1, i, 64);
                float hy1 = __shfl(y1, i, 64);
                float ha  = __shfl(ar, i, 64);
                float lx = fmaxf(hx0, x0), ly = fmaxf(hy0, y0);
                float rx = fminf(hx1, x1), ry = fminf(hy1, y1);
                float ww2 = fmaxf(rx - lx, 0.0f);
                float hh2 = fmaxf(ry - ly, 0.0f);
                float inter = ww2 * hh2;
                float denom = ha + ar;
                denom = denom - inter;
                denom = denom + 1e-7f;
                bool s = (lane > i) && (lane < n) && (inter / denom > IOU_T);
                colm |= ((u64)s) << i;
            }
            // phase 2: resolve (bit ops + ballot only)
            u64 alive = (n >= 64) ? ~0ull : ((1ull << n) - 1ull);
            for (int i = 0; i < n; ++i) {
                if (!((alive >> i) & 1ull)) continue;
                alive &= ~__ballot((colm >> i) & 1ull);
            }
            if (lane < n) keep[j] = (unsigned char)((alive >> lane) & 1ull);
        } else if (lane == 0) {
            // general fallback (n > 64): serial greedy, exact order
            for (int i = 0; i < TOPK; ++i) {
                if (lb8[i] != (unsigned char)c || !keep[i]) continue;
                float ax0 = offb[i][0], ay0 = offb[i][1];
                float ax1 = offb[i][2], ay1 = offb[i][3];
                float aa = area_s[i];
                for (int j2 = i + 1; j2 < TOPK; ++j2) {
                    if (lb8[j2] != (unsigned char)c || !keep[j2]) continue;
                    float lx = fmaxf(ax0, offb[j2][0]);
                    float ly = fmaxf(ay0, offb[j2][1]);
                    float rx = fminf(ax1, offb[j2][2]);
                    float ry = fminf(ay1, offb[j2][3]);
                    float ww2 = fmaxf(rx - lx, 0.0f);
                    float hh2 = fmaxf(ry - ly, 0.0f);
                    float inter = ww2 * hh2;
                    float denom = aa + area_s[j2];
                    denom = denom - inter;
                    denom = denom + 1e-7f;
                    if (inter / denom > IOU_T) keep[j2] = 0;
                }
            }
        }
    }
    __syncthreads();

    // ---- kept entries in sorted order ARE top_k(fin_s) order: ballot-scan ----
    bool valid = false;
    float sj = 0.0f;
    if (t < TOPK) {
        u32 u = (u32)(myk >> 14);
        u32 fb = (u & 0x80000000u) ? (u ^ 0x80000000u) : ~u;
        sj = __uint_as_float(fb);
        valid = keep[t] && (sj > CONF);
    }
    u64 m = __ballot(valid);
    if (lane == 0) wsum[wid] = (int)__popcll(m);
    __syncthreads();
    if (wid == 0) {
        int v = (lane < 16) ? wsum[lane] : 0;
        #pragma unroll
        for (int off = 1; off < 16; off <<= 1) {
            int o = __shfl_up(v, off, 64);
            if (lane >= off) v += o;
        }
        if (lane < 16) woff[lane] = v - wsum[lane];
        if (lane == 15) ktot_s = v;
    }
    __syncthreads();
    int ktot = ktot_s;
    int rank = woff[wid] + (int)__popcll(m & ((1ull << lane) - 1ull));

    float* out_boxes = out;
    float* out_scores = out + (size_t)BATCH * MAXDET * 4;
    float* out_labels = out + (size_t)BATCH * MAXDET * 5;
    if (valid && rank < MAXDET) {
        float4 bx = boxes[(size_t)b * NA + my_a];
        float* ob = out_boxes + ((size_t)b * MAXDET + rank) * 4;
        ob[0] = bx.x; ob[1] = bx.y; ob[2] = bx.z; ob[3] = bx.w;
        out_scores[(size_t)b * MAXDET + rank] = sj;
        out_labels[(size_t)b * MAXDET + rank] = coco_map_f[my_L];
    }
    if (t < MAXDET && t >= ktot) {
        float* ob = out_boxes + ((size_t)b * MAXDET + t) * 4;
        ob[0] = 0.0f; ob[1] = 0.0f; ob[2] = 0.0f; ob[3] = 0.0f;
        out_scores[(size_t)b * MAXDET + t] = 0.0f;
        out_labels[(size_t)b * MAXDET + t] = 0.0f;
    }
}

// ---------------------------------------------------------------------------
extern "C" void kernel_launch(void* const* d_in, const int* in_sizes, int n_in,
                              void* d_out, int out_size, void* d_ws, size_t ws_size,
                              hipStream_t stream) {
    const float* preds = (const float*)d_in[0];
    char* ws = (char*)d_ws;

    const size_t keys_bytes = (size_t)BATCH * NA * 8;    // 2,150,400
    const size_t boxes_bytes = (size_t)BATCH * NA * 16;  // 4,300,800

    u64* keys = (u64*)ws;
    float4* boxes = (float4*)(ws + keys_bytes);
    int* labels = (int*)(ws + keys_bytes + boxes_bytes);
    float* out = (float*)d_out;

    int total = BATCH * (NA / 4);
    decode_kernel<<<(total + 255) / 256, 256, 0, stream>>>(preds, keys, boxes, labels);
    select_nms_kernel<<<BATCH, NT, 0, stream>>>(keys, boxes, labels, out);
}

// Round 7
// 187.813 us; speedup vs baseline: 1.0289x; 1.0289x over previous
//
#include <hip/hip_runtime.h>
#include <stdint.h>

typedef unsigned long long u64;
typedef unsigned int u32;

#define BATCH 32
#define NCH 84
#define NA 8400
#define NCLS 80
#define TOPK 1000
#define MAXDET 300
#define CONF 0.25f
#define IOU_T 0.7f
#define MAX_WH 7680.0f
#define IMG_SZ 640.0f
#define NT 1024
#define KPT 9            // ceil(NA / NT)
#define NCOPY 8          // privatized histogram copies (fallback path)
#define HPAD 260         // 16B-aligned rows, bank-staggered copies

__device__ __constant__ float coco_map_f[NCLS] = {
    1,2,3,4,5,6,7,8,9,10,11,13,14,15,16,17,18,19,20,21,22,23,24,25,27,28,
    31,32,33,34,35,36,37,38,39,40,41,42,43,44,46,47,48,49,50,51,52,53,54,
    55,56,57,58,59,60,61,62,63,64,65,67,70,72,73,74,75,76,77,78,79,80,81,
    82,84,85,86,87,88,89,90};

__device__ inline u64 shflx64(u64 v, int m) {
    int lo = __shfl_xor((int)(u32)(v & 0xFFFFFFFFull), m, 64);
    int hi = __shfl_xor((int)(u32)(v >> 32), m, 64);
    return ((u64)(u32)hi << 32) | (u32)lo;
}

// ---------------- K1: decode 4 anchors/thread via float4 ---------------------
__global__ __launch_bounds__(256)
void decode_kernel(const float* __restrict__ preds,
                   u64* __restrict__ keys,
                   float4* __restrict__ boxes,
                   int* __restrict__ labels) {
    const int QPB = NA / 4;                       // 2100 quads per batch
    int gid = blockIdx.x * 256 + threadIdx.x;
    if (gid >= BATCH * QPB) return;
    int b = gid / QPB;
    int q = gid - b * QPB;
    int a0 = q * 4;
    const float* p = preds + (size_t)b * NCH * NA + a0;

    float4 x = *(const float4*)(p);
    float4 y = *(const float4*)(p + NA);
    float4 w = *(const float4*)(p + 2 * NA);
    float4 h = *(const float4*)(p + 3 * NA);

    float4 best = *(const float4*)(p + 4 * NA);
    int lx = 0, ly = 0, lz = 0, lw = 0;
#pragma unroll 16
    for (int c = 1; c < NCLS; ++c) {
        const float4 v = *(const float4*)(p + (size_t)(4 + c) * NA);
        lx = (v.x > best.x) ? c : lx;  best.x = fmaxf(v.x, best.x);
        ly = (v.y > best.y) ? c : ly;  best.y = fmaxf(v.y, best.y);
        lz = (v.z > best.z) ? c : lz;  best.z = fmaxf(v.z, best.z);
        lw = (v.w > best.w) ? c : lw;  best.w = fmaxf(v.w, best.w);
    }

    float bs[4] = {best.x, best.y, best.z, best.w};
    int   bl[4] = {lx, ly, lz, lw};
    float cx[4] = {x.x, x.y, x.z, x.w};
    float cy[4] = {y.x, y.y, y.z, y.w};
    float cw[4] = {w.x, w.y, w.z, w.w};
    float ch[4] = {h.x, h.y, h.z, h.w};

    u64* kp = keys + (size_t)b * NA + a0;
    float4* bp = boxes + (size_t)b * NA + a0;
    int* lp = labels + (size_t)b * NA + a0;

#pragma unroll
    for (int i = 0; i < 4; ++i) {
        float fx = cx[i] * IMG_SZ, fy = cy[i] * IMG_SZ;
        float fw = cw[i] * IMG_SZ, fh = ch[i] * IMG_SZ;
        float hw = fw * 0.5f, hh = fh * 0.5f;
        bp[i] = make_float4(fx - hw, fy - hh, fx + hw, fy + hh);
        float s = (bs[i] > CONF) ? bs[i] : -1.0f;
        u32 fb = __float_as_uint(s);
        u32 u = (fb & 0x80000000u) ? ~fb : (fb | 0x80000000u);
        // 46-bit key: sortable score bits << 14 | inverted anchor index
        kp[i] = ((u64)u << 14) | (u64)(16383 - (a0 + i));
    }
    *(int4*)lp = make_int4(bl[0], bl[1], bl[2], bl[3]);
}

// -------- K2a: per-batch radix-select + bitonic sort -> sorted keys ----------
__global__ __launch_bounds__(NT)
void topk_sort_kernel(const u64* __restrict__ keys,
                      u64* __restrict__ sorted) {
    const int b = blockIdx.x;
    const int t = threadIdx.x;
    const int lane = t & 63, wid = t >> 6;

    __shared__ u64 sk[2][NT];                       // 16 KB (double-buffer sort)
    __shared__ int sh_hist[NCOPY * HPAD];           // 8.3 KB (fallback only)
    __shared__ int selB, selK, hselS, smax, scnt, cnt;

    // ---- load this batch's keys (<=9 per thread, stays in VGPRs) ----
    u64 kreg[KPT];
    const u64* kb = keys + (size_t)b * NA;
    int nk = 0;
    for (int i = t; i < NA; i += NT) kreg[nk++] = kb[i];

    // ---- MSB-first radix select; degenerate passes use max-byte shortcut ----
    u64 P = 0ull;
    int kk = TOPK;
    int nsel = 0;
    for (int d = 5; d >= 0; --d) {
        __syncthreads();                 // protect smax/scnt from prior readers
        if (t == 0) { smax = -1; scnt = 0; }
        __syncthreads();
        u64 hmask = (~0ull) << (8 * (d + 1));
        int dig[KPT];
        int mymax = -1;
#pragma unroll
        for (int i = 0; i < KPT; ++i) {
            bool act = (i < nk) && (((kreg[i] ^ P) & hmask) == 0ull);
            dig[i] = act ? (int)((kreg[i] >> (8 * d)) & 255) : -1;
            mymax = max(mymax, dig[i]);
        }
#pragma unroll
        for (int off = 32; off; off >>= 1)
            mymax = max(mymax, __shfl_down(mymax, off, 64));
        if (lane == 0) atomicMax(&smax, mymax);
        __syncthreads();
        int maxb = smax;
        int myc = 0;
#pragma unroll
        for (int i = 0; i < KPT; ++i) myc += (dig[i] == maxb) ? 1 : 0;
#pragma unroll
        for (int off = 32; off; off >>= 1) myc += __shfl_down(myc, off, 64);
        if (lane == 0) atomicAdd(&scnt, myc);
        __syncthreads();
        int cm = scnt;
        if (cm >= kk) {
            // shortcut: selB = max digit, zero "above", kk unchanged
            P |= ((u64)maxb) << (8 * d);
            nsel = TOPK - kk + cm;
            if (nsel <= NT) break;
            continue;
        }
        // ---- fallback: full histogram pass (spread digits, low contention) --
        for (int i = t; i < NCOPY * HPAD; i += NT) sh_hist[i] = 0;
        __syncthreads();
        int* myh = sh_hist + (wid & (NCOPY - 1)) * HPAD;
#pragma unroll
        for (int i = 0; i < KPT; ++i)
            if (dig[i] >= 0) atomicAdd(&myh[dig[i]], 1);
        __syncthreads();
        if (t < 64) {
            int h0 = 0, h1 = 0, h2 = 0, h3 = 0;
            for (int c = 0; c < NCOPY; ++c) {
                const int* hp = sh_hist + c * HPAD + 4 * t;   // 16B-aligned
                h0 += hp[0]; h1 += hp[1]; h2 += hp[2]; h3 += hp[3];
            }
            int s = h0 + h1 + h2 + h3;
            int S = s;                       // wave suffix-scan, no barriers
            #pragma unroll
            for (int off = 1; off < 64; off <<= 1) {
                int o = __shfl_down(S, off, 64);
                if (t + off < 64) S += o;
            }
            int Snext = S - s;
            int c3 = Snext + h3, c2 = c3 + h2, c1 = c2 + h1, c0 = c1 + h0;
            int cand = -1, above = 0;
            if (c0 >= kk) {
                if      (c3 >= kk) { cand = 4 * t + 3; above = Snext; }
                else if (c2 >= kk) { cand = 4 * t + 2; above = c3; }
                else if (c1 >= kk) { cand = 4 * t + 1; above = c2; }
                else               { cand = 4 * t;     above = c1; }
            }
            int pc = (cand < 0) ? 0 : (((cand + 1) << 16) | (kk - above));
            #pragma unroll
            for (int off = 32; off; off >>= 1)
                pc = max(pc, __shfl_down(pc, off, 64));
            pc = __shfl(pc, 0, 64);
            int B = (pc >> 16) - 1;
            if (t == (B >> 2)) {
                int m4 = B & 3;
                selB = B;
                selK = pc & 0xFFFF;
                hselS = (m4 == 0) ? h0 : (m4 == 1) ? h1 : (m4 == 2) ? h2 : h3;
            }
        }
        __syncthreads();
        P |= ((u64)selB) << (8 * d);
        kk = selK;
        nsel = TOPK - kk + hselS;
        if (nsel <= NT) break;
    }

    // ---- compact the nsel (1000..1024) keys >= P (wave-aggregated) ----
    __syncthreads();
    if (t == 0) cnt = 0;
    __syncthreads();
    for (int i = 0; i < KPT; ++i) {
        bool p = (i < nk) && (kreg[i] >= P);
        u64 m = __ballot(p);
        int base = 0;
        if (lane == 0) base = atomicAdd(&cnt, (int)__popcll(m));
        base = __shfl(base, 0, 64);
        if (p) sk[0][base + (int)__popcll(m & ((1ull << lane) - 1ull))] = kreg[i];
    }
    if (t < NT - nsel) sk[0][nsel + t] = 0ull;
    __syncthreads();

    // ---- hybrid bitonic sort, descending; LDS stages double-buffered ----
    u64 myk = sk[0][t];
    int buf = 1;
    for (int size = 2; size <= NT; size <<= 1) {
        bool up = ((t & size) == 0);
        for (int stride = size >> 1; stride; stride >>= 1) {
            u64 pk;
            if (stride >= 64) {
                sk[buf][t] = myk;
                __syncthreads();
                pk = sk[buf][t ^ stride];
                buf ^= 1;
            } else {
                pk = shflx64(myk, stride);
            }
            bool tlow = ((t & stride) == 0);
            u64 mn = (myk < pk) ? myk : pk;
            u64 mx = (myk < pk) ? pk : myk;
            myk = up ? (tlow ? mx : mn) : (tlow ? mn : mx);
        }
    }
    sorted[(size_t)b * NT + t] = myk;    // rank t key (ranks >= TOPK unused)
}

// -------- K2b: gather + per-class NMS + epilogue -----------------------------
__global__ __launch_bounds__(NT)
void nms_kernel(const u64* __restrict__ sorted,
                const float4* __restrict__ boxes,
                const int* __restrict__ labels,
                float* __restrict__ out) {
    const int b = blockIdx.x;
    const int t = threadIdx.x;
    const int lane = t & 63, wid = t >> 6;

    __shared__ float offb[TOPK][4];                 // 16 KB  (offset boxes)
    __shared__ float area_s[TOPK];                  // 4 KB
    __shared__ unsigned char lb8[TOPK];             // 1 KB
    __shared__ unsigned char keep[TOPK];            // 1 KB
    __shared__ u64 cmask2[NCLS][16];                // 10 KB  (class membership)
    __shared__ unsigned short rows[NCLS][64];       // 10 KB  (per-class lists)
    __shared__ int ktot_s;
    __shared__ int wsum[16], woff[16];

    u64 myk = sorted[(size_t)b * NT + t];

    for (int i = t; i < NCLS * 16; i += NT) ((u64*)cmask2)[i] = 0ull;
    __syncthreads();

    // ---- gather payloads for sorted rank t ----
    int my_a = -1, my_L = 0;
    if (t < TOPK) {
        my_a = 16383 - (int)(myk & 16383ull);
        my_L = labels[(size_t)b * NA + my_a];
        lb8[t] = (unsigned char)my_L;
        float4 bx = boxes[(size_t)b * NA + my_a];
        float off = (float)my_L * MAX_WH;
        float ox0 = bx.x + off, oy0 = bx.y + off, ox1 = bx.z + off, oy1 = bx.w + off;
        offb[t][0] = ox0; offb[t][1] = oy0; offb[t][2] = ox1; offb[t][3] = oy1;
        area_s[t] = (ox1 - ox0) * (oy1 - oy0);   // ref: area on offset boxes
        keep[t] = 1;
        atomicOr(&cmask2[my_L][t >> 6], 1ull << (t & 63));
    }
    __syncthreads();

    // ---- NMS: one wave per class; membership from bitmask, boxes in regs ----
    for (int c = wid; c < NCLS; c += 16) {
        u64 w = (lane < 16) ? cmask2[c][lane] : 0ull;
        int cw = __popcll(w);
        int pre = cw;
        #pragma unroll
        for (int off = 1; off < 16; off <<= 1) {
            int o = __shfl_up(pre, off, 64);
            if (lane >= off) pre += o;
        }
        int n = __shfl(pre, 15, 64);
        pre -= cw;                           // exclusive prefix
        if (n == 0) continue;
        if (n <= 64) {
            if (lane < 16) {                 // emit rank list from mask bits
                u64 ww = w; int base = pre, boff = lane << 6;
                while (ww) {
                    int bit = __ffsll((long long)ww) - 1;
                    ww &= ww - 1;
                    rows[c][base++] = (unsigned short)(boff + bit);
                }
            }
            int j = (lane < n) ? (int)rows[c][lane] : (int)rows[c][0];
            float x0 = offb[j][0], y0 = offb[j][1];
            float x1 = offb[j][2], y1 = offb[j][3];
            float ar = area_s[j];
            // phase 1: colmask (no loop-carried dependence -> pipelined)
            u64 colm = 0ull;
            for (int i = 0; i < n; ++i) {
                float hx0 = __shfl(x0, i, 64);
                float hy0 = __shfl(y0, i, 64);
                float hx1 = __shfl(x1, i, 64);
                float hy1 = __shfl(y1, i, 64);
                float ha  = __shfl(ar, i, 64);
                float lx = fmaxf(hx0, x0), ly = fmaxf(hy0, y0);
                float rx = fminf(hx1, x1), ry = fminf(hy1, y1);
                float ww2 = fmaxf(rx - lx, 0.0f);
                float hh2 = fmaxf(ry - ly, 0.0f);
                float inter = ww2 * hh2;
                float denom = ha + ar;
                denom = denom - inter;
                denom = denom + 1e-7f;
                bool s = (lane > i) && (lane < n) && (inter / denom > IOU_T);
                colm |= ((u64)s) << i;
            }
            // phase 2: resolve (bit ops + ballot only)
            u64 alive = (n >= 64) ? ~0ull : ((1ull << n) - 1ull);
            for (int i = 0; i < n; ++i) {
                if (!((alive >> i) & 1ull)) continue;
                alive &= ~__ballot((colm >> i) & 1ull);
            }
            if (lane < n) keep[j] = (unsigned char)((alive >> lane) & 1ull);
        } else if (lane == 0) {
            // general fallback (n > 64): serial greedy, exact order
            for (int i = 0; i < TOPK; ++i) {
                if (lb8[i] != (unsigned char)c || !keep[i]) continue;
                float ax0 = offb[i][0], ay0 = offb[i][1];
                float ax1 = offb[i][2], ay1 = offb[i][3];
                float aa = area_s[i];
                for (int j2 = i + 1; j2 < TOPK; ++j2) {
                    if (lb8[j2] != (unsigned char)c || !keep[j2]) continue;
                    float lx = fmaxf(ax0, offb[j2][0]);
                    float ly = fmaxf(ay0, offb[j2][1]);
                    float rx = fminf(ax1, offb[j2][2]);
                    float ry = fminf(ay1, offb[j2][3]);
                    float ww2 = fmaxf(rx - lx, 0.0f);
                    float hh2 = fmaxf(ry - ly, 0.0f);
                    float inter = ww2 * hh2;
                    float denom = aa + area_s[j2];
                    denom = denom - inter;
                    denom = denom + 1e-7f;
                    if (inter / denom > IOU_T) keep[j2] = 0;
                }
            }
        }
    }
    __syncthreads();

    // ---- kept entries in sorted order ARE top_k(fin_s) order: ballot-scan ----
    bool valid = false;
    float sj = 0.0f;
    if (t < TOPK) {
        u32 u = (u32)(myk >> 14);
        u32 fb = (u & 0x80000000u) ? (u ^ 0x80000000u) : ~u;
        sj = __uint_as_float(fb);
        valid = keep[t] && (sj > CONF);
    }
    u64 m = __ballot(valid);
    if (lane == 0) wsum[wid] = (int)__popcll(m);
    __syncthreads();
    if (wid == 0) {
        int v = (lane < 16) ? wsum[lane] : 0;
        #pragma unroll
        for (int off = 1; off < 16; off <<= 1) {
            int o = __shfl_up(v, off, 64);
            if (lane >= off) v += o;
        }
        if (lane < 16) woff[lane] = v - wsum[lane];
        if (lane == 15) ktot_s = v;
    }
    __syncthreads();
    int ktot = ktot_s;
    int rank = woff[wid] + (int)__popcll(m & ((1ull << lane) - 1ull));

    float* out_boxes = out;
    float* out_scores = out + (size_t)BATCH * MAXDET * 4;
    float* out_labels = out + (size_t)BATCH * MAXDET * 5;
    if (valid && rank < MAXDET) {
        float4 bx = boxes[(size_t)b * NA + my_a];
        float* ob = out_boxes + ((size_t)b * MAXDET + rank) * 4;
        ob[0] = bx.x; ob[1] = bx.y; ob[2] = bx.z; ob[3] = bx.w;
        out_scores[(size_t)b * MAXDET + rank] = sj;
        out_labels[(size_t)b * MAXDET + rank] = coco_map_f[my_L];
    }
    if (t < MAXDET && t >= ktot) {
        float* ob = out_boxes + ((size_t)b * MAXDET + t) * 4;
        ob[0] = 0.0f; ob[1] = 0.0f; ob[2] = 0.0f; ob[3] = 0.0f;
        out_scores[(size_t)b * MAXDET + t] = 0.0f;
        out_labels[(size_t)b * MAXDET + t] = 0.0f;
    }
}

// ---------------------------------------------------------------------------
extern "C" void kernel_launch(void* const* d_in, const int* in_sizes, int n_in,
                              void* d_out, int out_size, void* d_ws, size_t ws_size,
                              hipStream_t stream) {
    const float* preds = (const float*)d_in[0];
    char* ws = (char*)d_ws;

    const size_t keys_bytes   = (size_t)BATCH * NA * 8;    // 2,150,400
    const size_t boxes_bytes  = (size_t)BATCH * NA * 16;   // 4,300,800
    const size_t labels_bytes = (size_t)BATCH * NA * 4;    // 1,075,200

    u64* keys = (u64*)ws;
    float4* boxes = (float4*)(ws + keys_bytes);
    int* labels = (int*)(ws + keys_bytes + boxes_bytes);
    u64* sorted = (u64*)(ws + keys_bytes + boxes_bytes + labels_bytes);
    float* out = (float*)d_out;

    int total = BATCH * (NA / 4);
    decode_kernel<<<(total + 255) / 256, 256, 0, stream>>>(preds, keys, boxes, labels);
    topk_sort_kernel<<<BATCH, NT, 0, stream>>>(keys, sorted);
    nms_kernel<<<BATCH, NT, 0, stream>>>(sorted, boxes, labels, out);
}

// Round 8
// 184.398 us; speedup vs baseline: 1.0480x; 1.0185x over previous
//
#include <hip/hip_runtime.h>
#include <stdint.h>

typedef unsigned long long u64;
typedef unsigned int u32;

#define BATCH 32
#define NCH 84
#define NA 8400
#define NCLS 80
#define TOPK 1000
#define MAXDET 300
#define CONF 0.25f
#define IOU_T 0.7f
#define MAX_WH 7680.0f
#define IMG_SZ 640.0f
#define NT 1024
#define KPT 9            // ceil(NA / NT)
#define NCOPY 8          // privatized histogram copies (fallback path)
#define HPAD 260         // 16B-aligned rows, bank-staggered copies
#define DTILE 256        // decode anchors per block

__device__ __constant__ float coco_map_f[NCLS] = {
    1,2,3,4,5,6,7,8,9,10,11,13,14,15,16,17,18,19,20,21,22,23,24,25,27,28,
    31,32,33,34,35,36,37,38,39,40,41,42,43,44,46,47,48,49,50,51,52,53,54,
    55,56,57,58,59,60,61,62,63,64,65,67,70,72,73,74,75,76,77,78,79,80,81,
    82,84,85,86,87,88,89,90};

__device__ inline u64 shflx64(u64 v, int m) {
    int lo = __shfl_xor((int)(u32)(v & 0xFFFFFFFFull), m, 64);
    int hi = __shfl_xor((int)(u32)(v >> 32), m, 64);
    return ((u64)(u32)hi << 32) | (u32)lo;
}

// ---- K1: decode via LDS transpose tiles (coalesced float4 + 16 waves/CU) ----
__global__ __launch_bounds__(256)
void decode_kernel(const float* __restrict__ preds,
                   u64* __restrict__ keys,
                   float4* __restrict__ boxes,
                   int* __restrict__ labels) {
    const int b = blockIdx.y;
    const int a_base = blockIdx.x * DTILE;
    const int t = threadIdx.x;
    const int a = a_base + t;
    const float* p = preds + (size_t)b * NCH * NA;

    __shared__ float stage[16][DTILE];   // 16 KB

    float bx = 0.f, by = 0.f, bw = 0.f, bh = 0.f;
    float best = -1.0f;
    int bl = 0;

    for (int chunk = 0; chunk < 6; ++chunk) {
        const int r0 = chunk * 16;
        const int nr = (chunk == 5) ? 4 : 16;       // 84 = 5*16 + 4
        if (chunk) __syncthreads();
        // cooperative load: nr rows x 256 anchors, float4-coalesced
        for (int i = 0; i < nr / 4; ++i) {
            int idx = i * 256 + t;
            int rl = idx >> 6;                      // 0..15
            int c4 = (idx & 63) * 4;
            int col = a_base + c4;
            float4 v = (col < NA) ? *(const float4*)(p + (size_t)(r0 + rl) * NA + col)
                                  : make_float4(0.f, 0.f, 0.f, 0.f);
            *(float4*)&stage[rl][c4] = v;
        }
        __syncthreads();
        // per-anchor consume (column reads: 2-way bank aliasing = free)
        if (chunk == 0) {
            bx = stage[0][t]; by = stage[1][t];
            bw = stage[2][t]; bh = stage[3][t];
            best = stage[4][t]; bl = 0;
            for (int r = 5; r < 16; ++r) {
                float v = stage[r][t];
                int c = r - 4;
                bl = (v > best) ? c : bl;  best = fmaxf(v, best);
            }
        } else {
            for (int r = 0; r < nr; ++r) {
                float v = stage[r][t];
                int c = r0 + r - 4;
                bl = (v > best) ? c : bl;  best = fmaxf(v, best);
            }
        }
    }

    if (a < NA) {
        float fx = bx * IMG_SZ, fy = by * IMG_SZ;
        float fw = bw * IMG_SZ, fh = bh * IMG_SZ;
        float hw = fw * 0.5f, hh = fh * 0.5f;
        boxes[(size_t)b * NA + a] = make_float4(fx - hw, fy - hh, fx + hw, fy + hh);
        float s = (best > CONF) ? best : -1.0f;
        u32 fb = __float_as_uint(s);
        u32 u = (fb & 0x80000000u) ? ~fb : (fb | 0x80000000u);
        // 46-bit key: sortable score bits << 14 | inverted anchor index
        keys[(size_t)b * NA + a] = ((u64)u << 14) | (u64)(16383 - a);
        labels[(size_t)b * NA + a] = bl;
    }
}

// ---- K2 (fused): radix-select + bitonic sort + gather + NMS + epilogue ------
__global__ __launch_bounds__(NT)
void select_nms_kernel(const u64* __restrict__ keys,
                       const float4* __restrict__ boxes,
                       const int* __restrict__ labels,
                       float* __restrict__ out) {
    const int b = blockIdx.x;
    const int t = threadIdx.x;
    const int lane = t & 63, wid = t >> 6;

    __shared__ union {
        struct {                                    // phase A: select + sort
            u64 sk[2][NT];                          // 16 KB
            int hist[NCOPY * HPAD];                 // 8.3 KB
        } a;
        struct {                                    // phase B: NMS
            float offb[TOPK][4];                    // 16 KB
            float area[TOPK];                       // 4 KB
            u64 cmask2[NCLS][16];                   // 10 KB
            unsigned short rows[NCLS][64];          // 10 KB
        } bb;
    } u_s;                                          // 39.5 KB
    __shared__ unsigned char lb8[TOPK];             // 1 KB
    __shared__ unsigned char keep[TOPK];            // 1 KB
    __shared__ int selB, selK, hselS, smax, scnt, cnt, ktot_s;
    __shared__ int wsum[16], woff[16];

    // ---- load this batch's keys (<=9 per thread, stays in VGPRs) ----
    u64 kreg[KPT];
    const u64* kb = keys + (size_t)b * NA;
    int nk = 0;
    for (int i = t; i < NA; i += NT) kreg[nk++] = kb[i];

    // ---- MSB-first radix select; degenerate passes use max-byte shortcut ----
    u64 P = 0ull;
    int kk = TOPK;
    int nsel = 0;
    for (int d = 5; d >= 0; --d) {
        __syncthreads();
        if (t == 0) { smax = -1; scnt = 0; }
        __syncthreads();
        u64 hmask = (~0ull) << (8 * (d + 1));
        int dig[KPT];
        int mymax = -1;
#pragma unroll
        for (int i = 0; i < KPT; ++i) {
            bool act = (i < nk) && (((kreg[i] ^ P) & hmask) == 0ull);
            dig[i] = act ? (int)((kreg[i] >> (8 * d)) & 255) : -1;
            mymax = max(mymax, dig[i]);
        }
#pragma unroll
        for (int off = 32; off; off >>= 1)
            mymax = max(mymax, __shfl_down(mymax, off, 64));
        if (lane == 0) atomicMax(&smax, mymax);
        __syncthreads();
        int maxb = smax;
        int myc = 0;
#pragma unroll
        for (int i = 0; i < KPT; ++i) myc += (dig[i] == maxb) ? 1 : 0;
#pragma unroll
        for (int off = 32; off; off >>= 1) myc += __shfl_down(myc, off, 64);
        if (lane == 0) atomicAdd(&scnt, myc);
        __syncthreads();
        int cm = scnt;
        if (cm >= kk) {
            P |= ((u64)maxb) << (8 * d);
            nsel = TOPK - kk + cm;
            if (nsel <= NT) break;
            continue;
        }
        // ---- fallback: full histogram pass (spread digits, low contention) --
        for (int i = t; i < NCOPY * HPAD; i += NT) u_s.a.hist[i] = 0;
        __syncthreads();
        int* myh = u_s.a.hist + (wid & (NCOPY - 1)) * HPAD;
#pragma unroll
        for (int i = 0; i < KPT; ++i)
            if (dig[i] >= 0) atomicAdd(&myh[dig[i]], 1);
        __syncthreads();
        if (t < 64) {
            int h0 = 0, h1 = 0, h2 = 0, h3 = 0;
            for (int c = 0; c < NCOPY; ++c) {
                const int* hp = u_s.a.hist + c * HPAD + 4 * t;   // 16B-aligned
                h0 += hp[0]; h1 += hp[1]; h2 += hp[2]; h3 += hp[3];
            }
            int s = h0 + h1 + h2 + h3;
            int S = s;                       // wave suffix-scan, no barriers
            #pragma unroll
            for (int off = 1; off < 64; off <<= 1) {
                int o = __shfl_down(S, off, 64);
                if (t + off < 64) S += o;
            }
            int Snext = S - s;
            int c3 = Snext + h3, c2 = c3 + h2, c1 = c2 + h1, c0 = c1 + h0;
            int cand = -1, above = 0;
            if (c0 >= kk) {
                if      (c3 >= kk) { cand = 4 * t + 3; above = Snext; }
                else if (c2 >= kk) { cand = 4 * t + 2; above = c3; }
                else if (c1 >= kk) { cand = 4 * t + 1; above = c2; }
                else               { cand = 4 * t;     above = c1; }
            }
            int pc = (cand < 0) ? 0 : (((cand + 1) << 16) | (kk - above));
            #pragma unroll
            for (int off = 32; off; off >>= 1)
                pc = max(pc, __shfl_down(pc, off, 64));
            pc = __shfl(pc, 0, 64);
            int B = (pc >> 16) - 1;
            if (t == (B >> 2)) {
                int m4 = B & 3;
                selB = B;
                selK = pc & 0xFFFF;
                hselS = (m4 == 0) ? h0 : (m4 == 1) ? h1 : (m4 == 2) ? h2 : h3;
            }
        }
        __syncthreads();
        P |= ((u64)selB) << (8 * d);
        kk = selK;
        nsel = TOPK - kk + hselS;
        if (nsel <= NT) break;
    }

    // ---- compact the nsel (1000..1024) keys >= P (wave-aggregated) ----
    __syncthreads();
    if (t == 0) cnt = 0;
    __syncthreads();
    for (int i = 0; i < KPT; ++i) {
        bool p = (i < nk) && (kreg[i] >= P);
        u64 m = __ballot(p);
        int base = 0;
        if (lane == 0) base = atomicAdd(&cnt, (int)__popcll(m));
        base = __shfl(base, 0, 64);
        if (p) u_s.a.sk[0][base + (int)__popcll(m & ((1ull << lane) - 1ull))] = kreg[i];
    }
    if (t < NT - nsel) u_s.a.sk[0][nsel + t] = 0ull;
    __syncthreads();

    // ---- hybrid bitonic sort, descending; LDS stages double-buffered ----
    u64 myk = u_s.a.sk[0][t];
    int buf = 1;
    for (int size = 2; size <= NT; size <<= 1) {
        bool up = ((t & size) == 0);
        for (int stride = size >> 1; stride; stride >>= 1) {
            u64 pk;
            if (stride >= 64) {
                u_s.a.sk[buf][t] = myk;
                __syncthreads();
                pk = u_s.a.sk[buf][t ^ stride];
                buf ^= 1;
            } else {
                pk = shflx64(myk, stride);
            }
            bool tlow = ((t & stride) == 0);
            u64 mn = (myk < pk) ? myk : pk;
            u64 mx = (myk < pk) ? pk : myk;
            myk = up ? (tlow ? mx : mn) : (tlow ? mn : mx);
        }
    }
    // myk == sorted key at rank t; ranks 0..999 are the exact top-1000.

    __syncthreads();                     // all waves done with sk -> reuse as B
    for (int i = t; i < NCLS * 16; i += NT) ((u64*)u_s.bb.cmask2)[i] = 0ull;
    __syncthreads();

    // ---- gather payloads for sorted rank t ----
    int my_a = -1, my_L = 0;
    if (t < TOPK) {
        my_a = 16383 - (int)(myk & 16383ull);
        my_L = labels[(size_t)b * NA + my_a];
        lb8[t] = (unsigned char)my_L;
        float4 bx = boxes[(size_t)b * NA + my_a];
        float off = (float)my_L * MAX_WH;
        float ox0 = bx.x + off, oy0 = bx.y + off, ox1 = bx.z + off, oy1 = bx.w + off;
        u_s.bb.offb[t][0] = ox0; u_s.bb.offb[t][1] = oy0;
        u_s.bb.offb[t][2] = ox1; u_s.bb.offb[t][3] = oy1;
        u_s.bb.area[t] = (ox1 - ox0) * (oy1 - oy0);   // ref: area on offset boxes
        keep[t] = 1;
        atomicOr(&u_s.bb.cmask2[my_L][t >> 6], 1ull << (t & 63));
    }
    __syncthreads();

    // ---- NMS: one wave per class; membership from bitmask, boxes in regs ----
    for (int c = wid; c < NCLS; c += 16) {
        u64 w = (lane < 16) ? u_s.bb.cmask2[c][lane] : 0ull;
        int cw = __popcll(w);
        int pre = cw;
        #pragma unroll
        for (int off = 1; off < 16; off <<= 1) {
            int o = __shfl_up(pre, off, 64);
            if (lane >= off) pre += o;
        }
        int n = __shfl(pre, 15, 64);
        pre -= cw;                           // exclusive prefix
        if (n == 0) continue;
        if (n <= 64) {
            if (lane < 16) {                 // emit rank list from mask bits
                u64 ww = w; int base = pre, boff = lane << 6;
                while (ww) {
                    int bit = __ffsll((long long)ww) - 1;
                    ww &= ww - 1;
                    u_s.bb.rows[c][base++] = (unsigned short)(boff + bit);
                }
            }
            int j = (lane < n) ? (int)u_s.bb.rows[c][lane] : (int)u_s.bb.rows[c][0];
            float x0 = u_s.bb.offb[j][0], y0 = u_s.bb.offb[j][1];
            float x1 = u_s.bb.offb[j][2], y1 = u_s.bb.offb[j][3];
            float ar = u_s.bb.area[j];
            // phase 1: colmask (no loop-carried dependence -> pipelined)
            u64 colm = 0ull;
            for (int i = 0; i < n; ++i) {
                float hx0 = __shfl(x0, i, 64);
                float hy0 = __shfl(y0, i, 64);
                float hx1 = __shfl(x1, i, 64);
                float hy1 = __shfl(y1, i, 64);
                float ha  = __shfl(ar, i, 64);
                float lx = fmaxf(hx0, x0), ly = fmaxf(hy0, y0);
                float rx = fminf(hx1, x1), ry = fminf(hy1, y1);
                float ww2 = fmaxf(rx - lx, 0.0f);
                float hh2 = fmaxf(ry - ly, 0.0f);
                float inter = ww2 * hh2;
                float denom = ha + ar;
                denom = denom - inter;
                denom = denom + 1e-7f;
                bool s = (lane > i) && (lane < n) && (inter / denom > IOU_T);
                colm |= ((u64)s) << i;
            }
            // phase 2: resolve (bit ops + ballot only)
            u64 alive = (n >= 64) ? ~0ull : ((1ull << n) - 1ull);
            for (int i = 0; i < n; ++i) {
                if (!((alive >> i) & 1ull)) continue;
                alive &= ~__ballot((colm >> i) & 1ull);
            }
            if (lane < n) keep[j] = (unsigned char)((alive >> lane) & 1ull);
        } else if (lane == 0) {
            // general fallback (n > 64): serial greedy, exact order
            for (int i = 0; i < TOPK; ++i) {
                if (lb8[i] != (unsigned char)c || !keep[i]) continue;
                float ax0 = u_s.bb.offb[i][0], ay0 = u_s.bb.offb[i][1];
                float ax1 = u_s.bb.offb[i][2], ay1 = u_s.bb.offb[i][3];
                float aa = u_s.bb.area[i];
                for (int j2 = i + 1; j2 < TOPK; ++j2) {
                    if (lb8[j2] != (unsigned char)c || !keep[j2]) continue;
                    float lx = fmaxf(ax0, u_s.bb.offb[j2][0]);
                    float ly = fmaxf(ay0, u_s.bb.offb[j2][1]);
                    float rx = fminf(ax1, u_s.bb.offb[j2][2]);
                    float ry = fminf(ay1, u_s.bb.offb[j2][3]);
                    float ww2 = fmaxf(rx - lx, 0.0f);
                    float hh2 = fmaxf(ry - ly, 0.0f);
                    float inter = ww2 * hh2;
                    float denom = aa + u_s.bb.area[j2];
                    denom = denom - inter;
                    denom = denom + 1e-7f;
                    if (inter / denom > IOU_T) keep[j2] = 0;
                }
            }
        }
    }
    __syncthreads();

    // ---- kept entries in sorted order ARE top_k(fin_s) order: ballot-scan ----
    bool valid = false;
    float sj = 0.0f;
    if (t < TOPK) {
        u32 u = (u32)(myk >> 14);
        u32 fb = (u & 0x80000000u) ? (u ^ 0x80000000u) : ~u;
        sj = __uint_as_float(fb);
        valid = keep[t] && (sj > CONF);
    }
    u64 m = __ballot(valid);
    if (lane == 0) wsum[wid] = (int)__popcll(m);
    __syncthreads();
    if (wid == 0) {
        int v = (lane < 16) ? wsum[lane] : 0;
        #pragma unroll
        for (int off = 1; off < 16; off <<= 1) {
            int o = __shfl_up(v, off, 64);
            if (lane >= off) v += o;
        }
        if (lane < 16) woff[lane] = v - wsum[lane];
        if (lane == 15) ktot_s = v;
    }
    __syncthreads();
    int ktot = ktot_s;
    int rank = woff[wid] + (int)__popcll(m & ((1ull << lane) - 1ull));

    float* out_boxes = out;
    float* out_scores = out + (size_t)BATCH * MAXDET * 4;
    float* out_labels = out + (size_t)BATCH * MAXDET * 5;
    if (valid && rank < MAXDET) {
        float4 bx = boxes[(size_t)b * NA + my_a];
        float* ob = out_boxes + ((size_t)b * MAXDET + rank) * 4;
        ob[0] = bx.x; ob[1] = bx.y; ob[2] = bx.z; ob[3] = bx.w;
        out_scores[(size_t)b * MAXDET + rank] = sj;
        out_labels[(size_t)b * MAXDET + rank] = coco_map_f[my_L];
    }
    if (t < MAXDET && t >= ktot) {
        float* ob = out_boxes + ((size_t)b * MAXDET + t) * 4;
        ob[0] = 0.0f; ob[1] = 0.0f; ob[2] = 0.0f; ob[3] = 0.0f;
        out_scores[(size_t)b * MAXDET + t] = 0.0f;
        out_labels[(size_t)b * MAXDET + t] = 0.0f;
    }
}

// ---------------------------------------------------------------------------
extern "C" void kernel_launch(void* const* d_in, const int* in_sizes, int n_in,
                              void* d_out, int out_size, void* d_ws, size_t ws_size,
                              hipStream_t stream) {
    const float* preds = (const float*)d_in[0];
    char* ws = (char*)d_ws;

    const size_t keys_bytes  = (size_t)BATCH * NA * 8;    // 2,150,400
    const size_t boxes_bytes = (size_t)BATCH * NA * 16;   // 4,300,800

    u64* keys = (u64*)ws;
    float4* boxes = (float4*)(ws + keys_bytes);
    int* labels = (int*)(ws + keys_bytes + boxes_bytes);
    float* out = (float*)d_out;

    dim3 dgrid((NA + DTILE - 1) / DTILE, BATCH);   // 33 x 32
    decode_kernel<<<dgrid, 256, 0, stream>>>(preds, keys, boxes, labels);
    select_nms_kernel<<<BATCH, NT, 0, stream>>>(keys, boxes, labels, out);
}

// Round 9
// 174.174 us; speedup vs baseline: 1.1095x; 1.0587x over previous
//
#include <hip/hip_runtime.h>
#include <stdint.h>

typedef unsigned long long u64;
typedef unsigned int u32;

#define BATCH 32
#define NCH 84
#define NA 8400
#define NCLS 80
#define TOPK 1000
#define MAXDET 300
#define CONF 0.25f
#define IOU_T 0.7f
#define MAX_WH 7680.0f
#define IMG_SZ 640.0f
#define NT 1024
#define KPT 9            // ceil(NA / NT)
#define NCOPY 8          // privatized histogram copies (fallback path)
#define HPAD 260         // 16B-aligned rows, bank-staggered copies
#define DTILE 256        // decode anchors per block

__device__ __constant__ float coco_map_f[NCLS] = {
    1,2,3,4,5,6,7,8,9,10,11,13,14,15,16,17,18,19,20,21,22,23,24,25,27,28,
    31,32,33,34,35,36,37,38,39,40,41,42,43,44,46,47,48,49,50,51,52,53,54,
    55,56,57,58,59,60,61,62,63,64,65,67,70,72,73,74,75,76,77,78,79,80,81,
    82,84,85,86,87,88,89,90};

__device__ inline u64 shflx64(u64 v, int m) {
    int lo = __shfl_xor((int)(u32)(v & 0xFFFFFFFFull), m, 64);
    int hi = __shfl_xor((int)(u32)(v >> 32), m, 64);
    return ((u64)(u32)hi << 32) | (u32)lo;
}

// ---- K1: decode via LDS transpose tiles (coalesced float4) ------------------
__global__ __launch_bounds__(256)
void decode_kernel(const float* __restrict__ preds,
                   u64* __restrict__ keys,
                   float4* __restrict__ boxes,
                   int* __restrict__ labels) {
    const int b = blockIdx.y;
    const int a_base = blockIdx.x * DTILE;
    const int t = threadIdx.x;
    const int a = a_base + t;
    const float* p = preds + (size_t)b * NCH * NA;

    __shared__ float stage[16][DTILE];   // 16 KB

    float bx = 0.f, by = 0.f, bw = 0.f, bh = 0.f;
    float best = -1.0f;
    int bl = 0;

    for (int chunk = 0; chunk < 6; ++chunk) {
        const int r0 = chunk * 16;
        const int nr = (chunk == 5) ? 4 : 16;       // 84 = 5*16 + 4
        if (chunk) __syncthreads();
        for (int i = 0; i < nr / 4; ++i) {
            int idx = i * 256 + t;
            int rl = idx >> 6;                      // 0..15
            int c4 = (idx & 63) * 4;
            int col = a_base + c4;
            float4 v = (col < NA) ? *(const float4*)(p + (size_t)(r0 + rl) * NA + col)
                                  : make_float4(0.f, 0.f, 0.f, 0.f);
            *(float4*)&stage[rl][c4] = v;
        }
        __syncthreads();
        if (chunk == 0) {
            bx = stage[0][t]; by = stage[1][t];
            bw = stage[2][t]; bh = stage[3][t];
            best = stage[4][t]; bl = 0;
            for (int r = 5; r < 16; ++r) {
                float v = stage[r][t];
                int c = r - 4;
                bl = (v > best) ? c : bl;  best = fmaxf(v, best);
            }
        } else {
            for (int r = 0; r < nr; ++r) {
                float v = stage[r][t];
                int c = r0 + r - 4;
                bl = (v > best) ? c : bl;  best = fmaxf(v, best);
            }
        }
    }

    if (a < NA) {
        float fx = bx * IMG_SZ, fy = by * IMG_SZ;
        float fw = bw * IMG_SZ, fh = bh * IMG_SZ;
        float hw = fw * 0.5f, hh = fh * 0.5f;
        boxes[(size_t)b * NA + a] = make_float4(fx - hw, fy - hh, fx + hw, fy + hh);
        float s = (best > CONF) ? best : -1.0f;
        u32 fb = __float_as_uint(s);
        u32 u = (fb & 0x80000000u) ? ~fb : (fb | 0x80000000u);
        keys[(size_t)b * NA + a] = ((u64)u << 14) | (u64)(16383 - a);
        labels[(size_t)b * NA + a] = bl;
    }
}

// ---- K2: radix-select + bitonic sort + gather -> class-compacted emit -------
__global__ __launch_bounds__(NT)
void select_sort_kernel(const u64* __restrict__ keys,
                        const float4* __restrict__ boxes,
                        const int* __restrict__ labels,
                        u64* __restrict__ sortedk,
                        float4* __restrict__ gbox,
                        float4* __restrict__ goffr,
                        float* __restrict__ garear,
                        unsigned char* __restrict__ lbr,
                        float4* __restrict__ goffb,
                        float* __restrict__ garea,
                        unsigned short* __restrict__ grank,
                        int* __restrict__ gccnt) {
    const int b = blockIdx.x;
    const int t = threadIdx.x;
    const int lane = t & 63, wid = t >> 6;

    __shared__ union {
        struct {                                    // phase A: select + sort
            u64 sk[2][NT];                          // 16 KB
            int hist[NCOPY * HPAD];                 // 8.3 KB
        } a;
        struct {                                    // phase B: classify
            u64 cmask2[NCLS][16];                   // 10 KB
        } bb;
    } u_s;
    __shared__ int selB, selK, hselS, smax, scnt, cnt;

    // ---- load this batch's keys ----
    u64 kreg[KPT];
    const u64* kb = keys + (size_t)b * NA;
    int nk = 0;
    for (int i = t; i < NA; i += NT) kreg[nk++] = kb[i];

    // ---- MSB-first radix select; degenerate passes use max-byte shortcut ----
    u64 P = 0ull;
    int kk = TOPK;
    int nsel = 0;
    for (int d = 5; d >= 0; --d) {
        __syncthreads();
        if (t == 0) { smax = -1; scnt = 0; }
        __syncthreads();
        u64 hmask = (~0ull) << (8 * (d + 1));
        int dig[KPT];
        int mymax = -1;
#pragma unroll
        for (int i = 0; i < KPT; ++i) {
            bool act = (i < nk) && (((kreg[i] ^ P) & hmask) == 0ull);
            dig[i] = act ? (int)((kreg[i] >> (8 * d)) & 255) : -1;
            mymax = max(mymax, dig[i]);
        }
#pragma unroll
        for (int off = 32; off; off >>= 1)
            mymax = max(mymax, __shfl_down(mymax, off, 64));
        if (lane == 0) atomicMax(&smax, mymax);
        __syncthreads();
        int maxb = smax;
        int myc = 0;
#pragma unroll
        for (int i = 0; i < KPT; ++i) myc += (dig[i] == maxb) ? 1 : 0;
#pragma unroll
        for (int off = 32; off; off >>= 1) myc += __shfl_down(myc, off, 64);
        if (lane == 0) atomicAdd(&scnt, myc);
        __syncthreads();
        int cm = scnt;
        if (cm >= kk) {
            P |= ((u64)maxb) << (8 * d);
            nsel = TOPK - kk + cm;
            if (nsel <= NT) break;
            continue;
        }
        // ---- fallback: full histogram pass ----
        for (int i = t; i < NCOPY * HPAD; i += NT) u_s.a.hist[i] = 0;
        __syncthreads();
        int* myh = u_s.a.hist + (wid & (NCOPY - 1)) * HPAD;
#pragma unroll
        for (int i = 0; i < KPT; ++i)
            if (dig[i] >= 0) atomicAdd(&myh[dig[i]], 1);
        __syncthreads();
        if (t < 64) {
            int h0 = 0, h1 = 0, h2 = 0, h3 = 0;
            for (int c = 0; c < NCOPY; ++c) {
                const int* hp = u_s.a.hist + c * HPAD + 4 * t;
                h0 += hp[0]; h1 += hp[1]; h2 += hp[2]; h3 += hp[3];
            }
            int s = h0 + h1 + h2 + h3;
            int S = s;
            #pragma unroll
            for (int off = 1; off < 64; off <<= 1) {
                int o = __shfl_down(S, off, 64);
                if (t + off < 64) S += o;
            }
            int Snext = S - s;
            int c3 = Snext + h3, c2 = c3 + h2, c1 = c2 + h1, c0 = c1 + h0;
            int cand = -1, above = 0;
            if (c0 >= kk) {
                if      (c3 >= kk) { cand = 4 * t + 3; above = Snext; }
                else if (c2 >= kk) { cand = 4 * t + 2; above = c3; }
                else if (c1 >= kk) { cand = 4 * t + 1; above = c2; }
                else               { cand = 4 * t;     above = c1; }
            }
            int pc = (cand < 0) ? 0 : (((cand + 1) << 16) | (kk - above));
            #pragma unroll
            for (int off = 32; off; off >>= 1)
                pc = max(pc, __shfl_down(pc, off, 64));
            pc = __shfl(pc, 0, 64);
            int B = (pc >> 16) - 1;
            if (t == (B >> 2)) {
                int m4 = B & 3;
                selB = B;
                selK = pc & 0xFFFF;
                hselS = (m4 == 0) ? h0 : (m4 == 1) ? h1 : (m4 == 2) ? h2 : h3;
            }
        }
        __syncthreads();
        P |= ((u64)selB) << (8 * d);
        kk = selK;
        nsel = TOPK - kk + hselS;
        if (nsel <= NT) break;
    }

    // ---- compact the nsel (1000..1024) keys >= P ----
    __syncthreads();
    if (t == 0) cnt = 0;
    __syncthreads();
    for (int i = 0; i < KPT; ++i) {
        bool p = (i < nk) && (kreg[i] >= P);
        u64 m = __ballot(p);
        int base = 0;
        if (lane == 0) base = atomicAdd(&cnt, (int)__popcll(m));
        base = __shfl(base, 0, 64);
        if (p) u_s.a.sk[0][base + (int)__popcll(m & ((1ull << lane) - 1ull))] = kreg[i];
    }
    if (t < NT - nsel) u_s.a.sk[0][nsel + t] = 0ull;
    __syncthreads();

    // ---- hybrid bitonic sort, descending ----
    u64 myk = u_s.a.sk[0][t];
    int buf = 1;
    for (int size = 2; size <= NT; size <<= 1) {
        bool up = ((t & size) == 0);
        for (int stride = size >> 1; stride; stride >>= 1) {
            u64 pk;
            if (stride >= 64) {
                u_s.a.sk[buf][t] = myk;
                __syncthreads();
                pk = u_s.a.sk[buf][t ^ stride];
                buf ^= 1;
            } else {
                pk = shflx64(myk, stride);
            }
            bool tlow = ((t & stride) == 0);
            u64 mn = (myk < pk) ? myk : pk;
            u64 mx = (myk < pk) ? pk : myk;
            myk = up ? (tlow ? mx : mn) : (tlow ? mn : mx);
        }
    }
    sortedk[(size_t)b * NT + t] = myk;

    __syncthreads();                     // done with sk -> reuse as cmask2
    for (int i = t; i < NCLS * 16; i += NT) ((u64*)u_s.bb.cmask2)[i] = 0ull;
    __syncthreads();

    // ---- gather + classify ----
    int my_L = 0;
    float4 bx = make_float4(0.f, 0.f, 0.f, 0.f);
    float ox0 = 0.f, oy0 = 0.f, ox1 = 0.f, oy1 = 0.f, ar = 0.f;
    if (t < TOPK) {
        int my_a = 16383 - (int)(myk & 16383ull);
        my_L = labels[(size_t)b * NA + my_a];
        bx = boxes[(size_t)b * NA + my_a];
        float off = (float)my_L * MAX_WH;
        ox0 = bx.x + off; oy0 = bx.y + off; ox1 = bx.z + off; oy1 = bx.w + off;
        ar = (ox1 - ox0) * (oy1 - oy0);   // ref: area on offset boxes
        atomicOr(&u_s.bb.cmask2[my_L][t >> 6], 1ull << (t & 63));
    }
    __syncthreads();
    if (t < TOPK) {
        int w = t >> 6;
        int r = __popcll(u_s.bb.cmask2[my_L][w] & ((1ull << (t & 63)) - 1ull));
        for (int q = 0; q < w; ++q) r += __popcll(u_s.bb.cmask2[my_L][q]);
        gbox[(size_t)b * NT + t] = bx;
        goffr[(size_t)b * NT + t] = make_float4(ox0, oy0, ox1, oy1);
        garear[(size_t)b * NT + t] = ar;
        lbr[(size_t)b * NT + t] = (unsigned char)my_L;
        if (r < 64) {
            size_t ci = ((size_t)b * NCLS + my_L) * 64 + r;
            goffb[ci] = make_float4(ox0, oy0, ox1, oy1);
            garea[ci] = ar;
            grank[ci] = (unsigned short)t;
        }
    }
    if (t < NCLS) {
        int s = 0;
#pragma unroll
        for (int q = 0; q < 16; ++q) s += __popcll(u_s.bb.cmask2[t][q]);
        gccnt[(size_t)b * NCLS + t] = s;
    }
}

// ---- K3: NMS, one (class,batch) per 64-thread block -------------------------
__global__ __launch_bounds__(64)
void nms_kernel(const float4* __restrict__ goffb,
                const float* __restrict__ garea,
                const unsigned short* __restrict__ grank,
                const int* __restrict__ gccnt,
                const float4* __restrict__ goffr,
                const float* __restrict__ garear,
                const unsigned char* __restrict__ lbr,
                unsigned char* __restrict__ keepg) {
    const int c = blockIdx.x;
    const int b = blockIdx.y;
    const int lane = threadIdx.x;
    const int n = gccnt[(size_t)b * NCLS + c];
    if (n == 0) return;

    if (n <= 64) {
        size_t ci = ((size_t)b * NCLS + c) * 64 + lane;
        float4 bb = make_float4(0.f, 0.f, 0.f, 0.f);
        float ar = 0.f;
        int rk = 0;
        if (lane < n) { bb = goffb[ci]; ar = garea[ci]; rk = grank[ci]; }
        // phase 1: colmask (independent iterations)
        u64 colm = 0ull;
        for (int i = 0; i < n; ++i) {
            float hx0 = __shfl(bb.x, i, 64);
            float hy0 = __shfl(bb.y, i, 64);
            float hx1 = __shfl(bb.z, i, 64);
            float hy1 = __shfl(bb.w, i, 64);
            float ha  = __shfl(ar, i, 64);
            float lx = fmaxf(hx0, bb.x), ly = fmaxf(hy0, bb.y);
            float rx = fminf(hx1, bb.z), ry = fminf(hy1, bb.w);
            float w = fmaxf(rx - lx, 0.0f);
            float h = fmaxf(ry - ly, 0.0f);
            float inter = w * h;
            float denom = ha + ar;
            denom = denom - inter;
            denom = denom + 1e-7f;
            bool s = (lane > i) && (lane < n) && (inter / denom > IOU_T);
            colm |= ((u64)s) << i;
        }
        // phase 2: resolve
        u64 alive = (n >= 64) ? ~0ull : ((1ull << n) - 1ull);
        for (int i = 0; i < n; ++i) {
            if (!((alive >> i) & 1ull)) continue;
            alive &= ~__ballot((colm >> i) & 1ull);
        }
        if (lane < n) keepg[(size_t)b * NT + rk] = (unsigned char)((alive >> lane) & 1ull);
    } else if (lane == 0) {
        // exact serial fallback over rank order (never taken in practice)
        u64 aliveW[16];
        for (int q = 0; q < 16; ++q) aliveW[q] = ~0ull;
        for (int i = 0; i < TOPK; ++i) {
            if (lbr[(size_t)b * NT + i] != (unsigned char)c) continue;
            if (!((aliveW[i >> 6] >> (i & 63)) & 1ull)) continue;
            float4 bi = goffr[(size_t)b * NT + i];
            float ai = garear[(size_t)b * NT + i];
            for (int j = i + 1; j < TOPK; ++j) {
                if (lbr[(size_t)b * NT + j] != (unsigned char)c) continue;
                if (!((aliveW[j >> 6] >> (j & 63)) & 1ull)) continue;
                float4 bj = goffr[(size_t)b * NT + j];
                float lx = fmaxf(bi.x, bj.x), ly = fmaxf(bi.y, bj.y);
                float rx = fminf(bi.z, bj.z), ry = fminf(bi.w, bj.w);
                float w = fmaxf(rx - lx, 0.0f);
                float h = fmaxf(ry - ly, 0.0f);
                float inter = w * h;
                float denom = ai + garear[(size_t)b * NT + j];
                denom = denom - inter;
                denom = denom + 1e-7f;
                if (inter / denom > IOU_T) aliveW[j >> 6] &= ~(1ull << (j & 63));
            }
        }
        for (int i = 0; i < TOPK; ++i)
            if (lbr[(size_t)b * NT + i] == (unsigned char)c)
                keepg[(size_t)b * NT + i] = (unsigned char)((aliveW[i >> 6] >> (i & 63)) & 1ull);
    }
}

// ---- K4: epilogue — rank-scan + output --------------------------------------
__global__ __launch_bounds__(NT)
void epilogue_kernel(const u64* __restrict__ sortedk,
                     const unsigned char* __restrict__ keepg,
                     const float4* __restrict__ gbox,
                     const unsigned char* __restrict__ lbr,
                     float* __restrict__ out) {
    const int b = blockIdx.x;
    const int t = threadIdx.x;
    const int lane = t & 63, wid = t >> 6;
    __shared__ int wsum[16], woff[16], ktot_s;

    u64 myk = sortedk[(size_t)b * NT + t];
    bool valid = false;
    float sj = 0.0f;
    if (t < TOPK) {
        u32 u = (u32)(myk >> 14);
        u32 fb = (u & 0x80000000u) ? (u ^ 0x80000000u) : ~u;
        sj = __uint_as_float(fb);
        valid = keepg[(size_t)b * NT + t] && (sj > CONF);
    }
    u64 m = __ballot(valid);
    if (lane == 0) wsum[wid] = (int)__popcll(m);
    __syncthreads();
    if (wid == 0) {
        int v = (lane < 16) ? wsum[lane] : 0;
        #pragma unroll
        for (int off = 1; off < 16; off <<= 1) {
            int o = __shfl_up(v, off, 64);
            if (lane >= off) v += o;
        }
        if (lane < 16) woff[lane] = v - wsum[lane];
        if (lane == 15) ktot_s = v;
    }
    __syncthreads();
    int ktot = ktot_s;
    int rank = woff[wid] + (int)__popcll(m & ((1ull << lane) - 1ull));

    float* out_boxes = out;
    float* out_scores = out + (size_t)BATCH * MAXDET * 4;
    float* out_labels = out + (size_t)BATCH * MAXDET * 5;
    if (valid && rank < MAXDET) {
        float4 bx = gbox[(size_t)b * NT + t];
        float* ob = out_boxes + ((size_t)b * MAXDET + rank) * 4;
        ob[0] = bx.x; ob[1] = bx.y; ob[2] = bx.z; ob[3] = bx.w;
        out_scores[(size_t)b * MAXDET + rank] = sj;
        out_labels[(size_t)b * MAXDET + rank] = coco_map_f[lbr[(size_t)b * NT + t]];
    }
    if (t < MAXDET && t >= ktot) {
        float* ob = out_boxes + ((size_t)b * MAXDET + t) * 4;
        ob[0] = 0.0f; ob[1] = 0.0f; ob[2] = 0.0f; ob[3] = 0.0f;
        out_scores[(size_t)b * MAXDET + t] = 0.0f;
        out_labels[(size_t)b * MAXDET + t] = 0.0f;
    }
}

// ---------------------------------------------------------------------------
extern "C" void kernel_launch(void* const* d_in, const int* in_sizes, int n_in,
                              void* d_out, int out_size, void* d_ws, size_t ws_size,
                              hipStream_t stream) {
    const float* preds = (const float*)d_in[0];
    char* ws = (char*)d_ws;
    size_t off = 0;
    auto alloc = [&](size_t bytes) { char* p = ws + off; off += (bytes + 255) & ~(size_t)255; return p; };

    u64* keys            = (u64*)           alloc((size_t)BATCH * NA * 8);
    float4* boxes        = (float4*)        alloc((size_t)BATCH * NA * 16);
    int* labels          = (int*)           alloc((size_t)BATCH * NA * 4);
    u64* sortedk         = (u64*)           alloc((size_t)BATCH * NT * 8);
    float4* gbox         = (float4*)        alloc((size_t)BATCH * NT * 16);
    float4* goffr        = (float4*)        alloc((size_t)BATCH * NT * 16);
    float* garear        = (float*)         alloc((size_t)BATCH * NT * 4);
    unsigned char* lbr   = (unsigned char*) alloc((size_t)BATCH * NT);
    float4* goffb        = (float4*)        alloc((size_t)BATCH * NCLS * 64 * 16);
    float* garea         = (float*)         alloc((size_t)BATCH * NCLS * 64 * 4);
    unsigned short* grank= (unsigned short*)alloc((size_t)BATCH * NCLS * 64 * 2);
    int* gccnt           = (int*)           alloc((size_t)BATCH * NCLS * 4);
    unsigned char* keepg = (unsigned char*) alloc((size_t)BATCH * NT);
    float* out = (float*)d_out;

    dim3 dgrid((NA + DTILE - 1) / DTILE, BATCH);   // 33 x 32
    decode_kernel<<<dgrid, 256, 0, stream>>>(preds, keys, boxes, labels);
    select_sort_kernel<<<BATCH, NT, 0, stream>>>(keys, boxes, labels, sortedk,
                                                 gbox, goffr, garear, lbr,
                                                 goffb, garea, grank, gccnt);
    dim3 ngrid(NCLS, BATCH);                       // 80 x 32
    nms_kernel<<<ngrid, 64, 0, stream>>>(goffb, garea, grank, gccnt,
                                         goffr, garear, lbr, keepg);
    epilogue_kernel<<<BATCH, NT, 0, stream>>>(sortedk, keepg, gbox, lbr, out);
}